// Round 1
// baseline (2536.548 us; speedup 1.0000x reference)
//
#include <hip/hip_runtime.h>

typedef _Float16 f16;
typedef _Float16 f16x8 __attribute__((ext_vector_type(8)));
typedef float    f32x4 __attribute__((ext_vector_type(4)));

#define CCH 66
#define LLEN 100
#define BSZ 4096
#define KPAD 7168
#define NPAD 2048
#define NOUT 1936
#define KFEAT 7128

// ---------------------------------------------------------------- async G->LDS
typedef unsigned int u32;
typedef __attribute__((address_space(1))) const u32 gu32;
typedef __attribute__((address_space(3))) u32 lu32;

__device__ __forceinline__ void gload_lds16(const void* g, void* l) {
    __builtin_amdgcn_global_load_lds((gu32*)g, (lu32*)l, 16, 0, 0);
}

// ---------------------------------------------------------------- feature pipeline
// hp1 column idx (0..49): pooled+relu'd conv1 outputs, 8 channels.
template<int K>
__device__ __forceinline__ void hp1_col(const float* __restrict__ xb, int idx,
                                        const float* __restrict__ w1,
                                        const float* __restrict__ b1,
                                        float col[8]) {
    constexpr int P = K / 2;
    if (idx < 50) {
        float xv[K + 1];
#pragma unroll
        for (int j = 0; j <= K; ++j) {
            int u = 2 * idx - P + j;
            xv[j] = (u >= 0 && u < LLEN) ? xb[(size_t)u * CCH] : 0.f;
        }
#pragma unroll
        for (int ic = 0; ic < 8; ++ic) {
            float a = b1[ic], b = b1[ic];
#pragma unroll
            for (int k = 0; k < K; ++k) {
                float w = w1[ic * K + k];
                a += w * xv[k];
                b += w * xv[k + 1];
            }
            col[ic] = 0.5f * (fmaxf(a, 0.f) + fmaxf(b, 0.f));
        }
    } else {
#pragma unroll
        for (int ic = 0; ic < 8; ++ic) col[ic] = 0.f;
    }
}

// Full branch: conv1(1->8,K)+pool -> conv2(8->4,K)+pool -> conv3(4->4,K)+pool
// Streaming: W1 holds hp1[2s-P .. 2s+P+1]; W2 holds hp2[s-2P .. s].
template<int K>
__device__ __forceinline__ void run_branch(const float* __restrict__ xb,
                                           const float* __restrict__ w1, const float* __restrict__ b1,
                                           const float* __restrict__ w2, const float* __restrict__ b2,
                                           const float* __restrict__ w3, const float* __restrict__ b3,
                                           f16* __restrict__ outp) {
    constexpr int P = K / 2;
    float W1[8][K + 1];
    float W2[4][K];
#pragma unroll
    for (int ic = 0; ic < 8; ++ic)
#pragma unroll
        for (int j = 0; j <= K; ++j) W1[ic][j] = 0.f;
#pragma unroll
    for (int oc = 0; oc < 4; ++oc)
#pragma unroll
        for (int j = 0; j < K; ++j) W2[oc][j] = 0.f;

    // prologue: W1[.][P+idx] = hp1[idx] for idx = 0..P+1
#pragma unroll
    for (int idx = 0; idx <= P + 1; ++idx) {
        float col[8];
        hp1_col<K>(xb, idx, w1, b1, col);
#pragma unroll
        for (int ic = 0; ic < 8; ++ic) W1[ic][P + idx] = col[ic];
    }

    float pacc[4] = {0.f, 0.f, 0.f, 0.f};
    const int SMAX = 23 + P;  // last y3 position p = 23
    for (int s = 0; s <= SMAX; ++s) {
        // hp2[s] from y2 at 2s, 2s+1
        float h2col[4];
        if (s <= 24) {
#pragma unroll
            for (int oc = 0; oc < 4; ++oc) {
                float ya = b2[oc], yb = b2[oc];
#pragma unroll
                for (int ic = 0; ic < 8; ++ic)
#pragma unroll
                    for (int k = 0; k < K; ++k) {
                        float w = w2[(oc * 8 + ic) * K + k];
                        ya += w * W1[ic][k];
                        yb += w * W1[ic][k + 1];
                    }
                h2col[oc] = 0.5f * (fmaxf(ya, 0.f) + fmaxf(yb, 0.f));
            }
        } else {
#pragma unroll
            for (int oc = 0; oc < 4; ++oc) h2col[oc] = 0.f;
        }
        // shift W2, append hp2[s]
#pragma unroll
        for (int oc = 0; oc < 4; ++oc) {
#pragma unroll
            for (int j = 0; j < K - 1; ++j) W2[oc][j] = W2[oc][j + 1];
            W2[oc][K - 1] = h2col[oc];
        }
        // y3 at p = s - P; pool pairs -> output t = p>>1
        int p = s - P;
        if (p >= 0) {
            float y3[4];
#pragma unroll
            for (int oc = 0; oc < 4; ++oc) {
                float y = b3[oc];
#pragma unroll
                for (int ic = 0; ic < 4; ++ic)
#pragma unroll
                    for (int k = 0; k < K; ++k)
                        y += w3[(oc * 4 + ic) * K + k] * W2[ic][k];
                y3[oc] = fmaxf(y, 0.f);
            }
            if ((p & 1) == 0) {
#pragma unroll
                for (int oc = 0; oc < 4; ++oc) pacc[oc] = y3[oc];
            } else {
                int t = p >> 1;
#pragma unroll
                for (int oc = 0; oc < 4; ++oc)
                    outp[oc * 12 + t] = (f16)(0.5f * (pacc[oc] + y3[oc]));
            }
        }
        // advance W1 by 2 columns
        if (s < SMAX) {
#pragma unroll
            for (int ic = 0; ic < 8; ++ic)
#pragma unroll
                for (int j = 0; j < K - 1; ++j) W1[ic][j] = W1[ic][j + 2];
            float colA[8], colB[8];
            hp1_col<K>(xb, 2 * s + P + 2, w1, b1, colA);
            hp1_col<K>(xb, 2 * s + P + 3, w1, b1, colB);
#pragma unroll
            for (int ic = 0; ic < 8; ++ic) {
                W1[ic][K - 1] = colA[ic];
                W1[ic][K]     = colB[ic];
            }
        }
    }
}

__global__ __launch_bounds__(64) void feats_kernel(
    const float* __restrict__ x,
    const float* __restrict__ hw1, const float* __restrict__ hb1,
    const float* __restrict__ hw2, const float* __restrict__ hb2,
    const float* __restrict__ hw3, const float* __restrict__ hb3,
    const float* __restrict__ lw1, const float* __restrict__ lb1,
    const float* __restrict__ lw2, const float* __restrict__ lb2,
    const float* __restrict__ lw3, const float* __restrict__ lb3,
    f16* __restrict__ featsH) {
    const int c = blockIdx.x;
    const int b = blockIdx.y * 64 + threadIdx.x;
    const float* xb = x + (size_t)b * (LLEN * CCH) + c;  // x[b][l][c] at xb[l*CCH]
    f16* outp = featsH + (size_t)b * KPAD + c * 108;

    // high branch (K=7): features 0..3
    run_branch<7>(xb, hw1 + c * 56, hb1 + c * 8, hw2 + c * 224, hb2 + c * 4,
                  hw3 + c * 112, hb3 + c * 4, outp);
    // low branch (K=3): features 4..7
    run_branch<3>(xb, lw1 + c * 24, lb1 + c * 8, lw2 + c * 96, lb2 + c * 4,
                  lw3 + c * 48, lb3 + c * 4, outp + 48);
    // residual pooling: feature 8
#pragma unroll
    for (int t = 0; t < 12; ++t) {
        float s = 0.f;
#pragma unroll
        for (int j = 0; j < 8; ++j) s += xb[(size_t)(8 * t + j) * CCH];
        outp[96 + t] = (f16)(s * 0.125f);
    }
}

// zero the K-padding columns of feats
__global__ void pad_feats(f16* __restrict__ featsH) {
    int b = blockIdx.x;
    int t = threadIdx.x;
    if (t < KPAD - KFEAT) featsH[(size_t)b * KPAD + KFEAT + t] = (f16)0.f;
}

// convert fw1 (1936 x 7128 f32) -> padded f16 (2048 x 7168), zero-filled pad
__global__ void cvt_fw1(const float* __restrict__ fw1, f16* __restrict__ dst) {
    int n = blockIdx.y;
    int k = blockIdx.x * 256 + threadIdx.x;
    float v = (n < NOUT && k < KFEAT) ? fw1[(size_t)n * KFEAT + k] : 0.f;
    dst[(size_t)n * KPAD + k] = (f16)v;
}

// ---------------------------------------------------------------- FC1 GEMM
// C[m][n] = sum_k A[m][k] * Bw[n][k];  H = relu(C + fb1) stored f16.
__global__ __launch_bounds__(256) void fc1_gemm(
    const f16* __restrict__ A, const f16* __restrict__ Bw,
    const float* __restrict__ fb1, f16* __restrict__ H) {
    __shared__ f16 lds_a[128 * 32];
    __shared__ f16 lds_b[128 * 32];
    const int tid = threadIdx.x;
    const int bm = blockIdx.x;  // 32 tiles of M
    const int bn = blockIdx.y;  // 16 tiles of N
    const int wid = tid >> 6, lane = tid & 63;
    const int wm = wid >> 1, wn = wid & 1;

    f32x4 acc[4][4];
#pragma unroll
    for (int i = 0; i < 4; ++i)
#pragma unroll
        for (int j = 0; j < 4; ++j) acc[i][j] = (f32x4){0.f, 0.f, 0.f, 0.f};

    const f16* Abase = A + (size_t)bm * 128 * KPAD;
    const f16* Bbase = Bw + (size_t)bn * 128 * KPAD;

    const int l15 = lane & 15, lhi = lane >> 4;

    for (int k0 = 0; k0 < KPAD; k0 += 32) {
        __syncthreads();
#pragma unroll
        for (int p = 0; p < 2; ++p) {
            int flat = p * 256 + tid;
            int row = flat >> 2, kc = flat & 3;
            gload_lds16(Abase + (size_t)row * KPAD + k0 + kc * 8, (char*)lds_a + flat * 16);
            gload_lds16(Bbase + (size_t)row * KPAD + k0 + kc * 8, (char*)lds_b + flat * 16);
        }
        __syncthreads();

        f16x8 af[4], bf[4];
#pragma unroll
        for (int i = 0; i < 4; ++i) {
            int m = wm * 64 + i * 16 + l15;
            af[i] = *(const f16x8*)(lds_a + m * 32 + lhi * 8);
            int n = wn * 64 + i * 16 + l15;
            bf[i] = *(const f16x8*)(lds_b + n * 32 + lhi * 8);
        }
#pragma unroll
        for (int i = 0; i < 4; ++i)
#pragma unroll
            for (int j = 0; j < 4; ++j)
                acc[i][j] = __builtin_amdgcn_mfma_f32_16x16x32_f16(af[i], bf[j], acc[i][j], 0, 0, 0);
    }

    // epilogue: C/D layout col = lane&15, row = (lane>>4)*4 + r
#pragma unroll
    for (int i = 0; i < 4; ++i) {
#pragma unroll
        for (int j = 0; j < 4; ++j) {
            int n = bn * 128 + wn * 64 + j * 16 + l15;
            float bias = (n < NOUT) ? fb1[n] : 0.f;
#pragma unroll
            for (int r = 0; r < 4; ++r) {
                int m = bm * 128 + wm * 64 + i * 16 + lhi * 4 + r;
                float v = acc[i][j][r] + bias;
                H[(size_t)m * NPAD + n] = (f16)fmaxf(v, 0.f);
            }
        }
    }
}

// ---------------------------------------------------------------- FC2
__global__ __launch_bounds__(64) void fc2_kernel(const f16* __restrict__ H,
                                                 const float* __restrict__ fw2,
                                                 const float* __restrict__ fb2,
                                                 float* __restrict__ out) {
    const int b = blockIdx.x;
    const int t = threadIdx.x;
    const f16* hb = H + (size_t)b * NPAD;
    float acc[14];
#pragma unroll
    for (int o = 0; o < 14; ++o) acc[o] = 0.f;
    for (int k = t; k < NOUT; k += 64) {
        float hv = (float)hb[k];
#pragma unroll
        for (int o = 0; o < 14; ++o) acc[o] += hv * fw2[o * NOUT + k];
    }
#pragma unroll
    for (int o = 0; o < 14; ++o) {
        float v = acc[o];
#pragma unroll
        for (int off = 32; off > 0; off >>= 1) v += __shfl_down(v, off, 64);
        if (t == 0) out[b * 14 + o] = v + fb2[o];
    }
}

// ---------------------------------------------------------------- launcher
extern "C" void kernel_launch(void* const* d_in, const int* in_sizes, int n_in,
                              void* d_out, int out_size, void* d_ws, size_t ws_size,
                              hipStream_t stream) {
    const float* x   = (const float*)d_in[0];
    const float* hw1 = (const float*)d_in[1];
    const float* hb1 = (const float*)d_in[2];
    const float* hw2 = (const float*)d_in[3];
    const float* hb2 = (const float*)d_in[4];
    const float* hw3 = (const float*)d_in[5];
    const float* hb3 = (const float*)d_in[6];
    const float* lw1 = (const float*)d_in[7];
    const float* lb1 = (const float*)d_in[8];
    const float* lw2 = (const float*)d_in[9];
    const float* lb2 = (const float*)d_in[10];
    const float* lw3 = (const float*)d_in[11];
    const float* lb3 = (const float*)d_in[12];
    const float* fw1 = (const float*)d_in[13];
    const float* fb1 = (const float*)d_in[14];
    const float* fw2 = (const float*)d_in[15];
    const float* fb2 = (const float*)d_in[16];

    f16* featsH = (f16*)d_ws;                               // 4096*7168 f16 = 58.7 MB
    f16* fw1H   = featsH + (size_t)BSZ * KPAD;              // 2048*7168 f16 = 29.4 MB
    f16* h      = fw1H + (size_t)NPAD * KPAD;               // 4096*2048 f16 = 16.8 MB

    feats_kernel<<<dim3(CCH, BSZ / 64), 64, 0, stream>>>(
        x, hw1, hb1, hw2, hb2, hw3, hb3, lw1, lb1, lw2, lb2, lw3, lb3, featsH);
    pad_feats<<<dim3(BSZ), 64, 0, stream>>>(featsH);
    cvt_fw1<<<dim3(KPAD / 256, NPAD), 256, 0, stream>>>(fw1, fw1H);
    fc1_gemm<<<dim3(BSZ / 128, NPAD / 128), 256, 0, stream>>>(featsH, fw1H, fb1, h);
    fc2_kernel<<<dim3(BSZ), 64, 0, stream>>>(h, fw2, fb2, (float*)d_out);
}

// Round 2
// 883.421 us; speedup vs baseline: 2.8713x; 2.8713x over previous
//
#include <hip/hip_runtime.h>

typedef _Float16 f16;
typedef _Float16 f16x8 __attribute__((ext_vector_type(8)));
typedef float    f32x4 __attribute__((ext_vector_type(4)));
typedef unsigned int u32;

#define CCH 66
#define LLEN 100
#define BSZ 4096
#define KPAD 7168
#define NPAD 2048
#define NOUT 1936
#define KFEAT 7128
#define XSTR (CCH * BSZ)   // element stride between successive l in xT

// ---------------------------------------------------------------- async G->LDS
typedef __attribute__((address_space(1))) const u32 gu32;
typedef __attribute__((address_space(3))) u32 lu32;

__device__ __forceinline__ void gload_lds16(const void* g, void* l) {
    __builtin_amdgcn_global_load_lds((gu32*)g, (lu32*)l, 16, 0, 0);
}

// ---------------------------------------------------------------- x transpose
// x [B][L*C] f32  ->  xT [L*C][B] f16   (element (l,c) row index = l*66+c)
#define LC (LLEN * CCH)
__global__ __launch_bounds__(256) void transpose_x(const float* __restrict__ x,
                                                   f16* __restrict__ xT) {
    __shared__ float tile[32][33];
    const int m0 = blockIdx.x * 32;           // lc index
    const int b0 = blockIdx.y * 32;           // batch index
    const int tx = threadIdx.x & 31, ty = threadIdx.x >> 5;  // 32 x 8
#pragma unroll
    for (int i = 0; i < 32; i += 8) {
        int m = m0 + tx, b = b0 + ty + i;
        tile[ty + i][tx] = (m < LC) ? x[(size_t)b * LC + m] : 0.f;
    }
    __syncthreads();
#pragma unroll
    for (int i = 0; i < 32; i += 8) {
        int m = m0 + ty + i, b = b0 + tx;
        if (m < LC) xT[(size_t)m * BSZ + b] = (f16)tile[tx][ty + i];
    }
}

// ---------------------------------------------------------------- feature pipeline
__device__ __forceinline__ float ldx(const f16* __restrict__ xb, int u) {
    return (float)xb[(size_t)u * XSTR];
}

// hp1 column idx (0..49): pooled+relu'd conv1 outputs, 8 channels.
template<int K>
__device__ __forceinline__ void hp1_col(const f16* __restrict__ xb, int idx,
                                        const float* __restrict__ w1,
                                        const float* __restrict__ b1,
                                        float col[8]) {
    constexpr int P = K / 2;
    if (idx < 50) {
        float xv[K + 1];
#pragma unroll
        for (int j = 0; j <= K; ++j) {
            int u = 2 * idx - P + j;
            xv[j] = (u >= 0 && u < LLEN) ? ldx(xb, u) : 0.f;
        }
#pragma unroll
        for (int ic = 0; ic < 8; ++ic) {
            float a = b1[ic], b = b1[ic];
#pragma unroll
            for (int k = 0; k < K; ++k) {
                float w = w1[ic * K + k];
                a += w * xv[k];
                b += w * xv[k + 1];
            }
            col[ic] = 0.5f * (fmaxf(a, 0.f) + fmaxf(b, 0.f));
        }
    } else {
#pragma unroll
        for (int ic = 0; ic < 8; ++ic) col[ic] = 0.f;
    }
}

// Full branch: conv1(1->8,K)+pool -> conv2(8->4,K)+pool -> conv3(4->4,K)+pool
// Streaming: W1 holds hp1[2s-P .. 2s+P+1]; W2 holds hp2[s-2P .. s].
template<int K>
__device__ __forceinline__ void run_branch(const f16* __restrict__ xb,
                                           const float* __restrict__ w1, const float* __restrict__ b1,
                                           const float* __restrict__ w2, const float* __restrict__ b2,
                                           const float* __restrict__ w3, const float* __restrict__ b3,
                                           f16* __restrict__ outp) {
    constexpr int P = K / 2;
    float W1[8][K + 1];
    float W2[4][K];
#pragma unroll
    for (int ic = 0; ic < 8; ++ic)
#pragma unroll
        for (int j = 0; j <= K; ++j) W1[ic][j] = 0.f;
#pragma unroll
    for (int oc = 0; oc < 4; ++oc)
#pragma unroll
        for (int j = 0; j < K; ++j) W2[oc][j] = 0.f;

    // prologue: W1[.][P+idx] = hp1[idx] for idx = 0..P+1
#pragma unroll
    for (int idx = 0; idx <= P + 1; ++idx) {
        float col[8];
        hp1_col<K>(xb, idx, w1, b1, col);
#pragma unroll
        for (int ic = 0; ic < 8; ++ic) W1[ic][P + idx] = col[ic];
    }

    float pacc[4] = {0.f, 0.f, 0.f, 0.f};
    const int SMAX = 23 + P;  // last y3 position p = 23
    for (int s = 0; s <= SMAX; ++s) {
        // hp2[s] from y2 at 2s, 2s+1
        float h2col[4];
        if (s <= 24) {
#pragma unroll
            for (int oc = 0; oc < 4; ++oc) {
                float ya = b2[oc], yb = b2[oc];
#pragma unroll
                for (int ic = 0; ic < 8; ++ic)
#pragma unroll
                    for (int k = 0; k < K; ++k) {
                        float w = w2[(oc * 8 + ic) * K + k];
                        ya += w * W1[ic][k];
                        yb += w * W1[ic][k + 1];
                    }
                h2col[oc] = 0.5f * (fmaxf(ya, 0.f) + fmaxf(yb, 0.f));
            }
        } else {
#pragma unroll
            for (int oc = 0; oc < 4; ++oc) h2col[oc] = 0.f;
        }
        // shift W2, append hp2[s]
#pragma unroll
        for (int oc = 0; oc < 4; ++oc) {
#pragma unroll
            for (int j = 0; j < K - 1; ++j) W2[oc][j] = W2[oc][j + 1];
            W2[oc][K - 1] = h2col[oc];
        }
        // y3 at p = s - P; pool pairs -> output t = p>>1
        int p = s - P;
        if (p >= 0) {
            float y3[4];
#pragma unroll
            for (int oc = 0; oc < 4; ++oc) {
                float y = b3[oc];
#pragma unroll
                for (int ic = 0; ic < 4; ++ic)
#pragma unroll
                    for (int k = 0; k < K; ++k)
                        y += w3[(oc * 4 + ic) * K + k] * W2[ic][k];
                y3[oc] = fmaxf(y, 0.f);
            }
            if ((p & 1) == 0) {
#pragma unroll
                for (int oc = 0; oc < 4; ++oc) pacc[oc] = y3[oc];
            } else {
                int t = p >> 1;
#pragma unroll
                for (int oc = 0; oc < 4; ++oc)
                    outp[oc * 12 + t] = (f16)(0.5f * (pacc[oc] + y3[oc]));
            }
        }
        // advance W1 by 2 columns
        if (s < SMAX) {
#pragma unroll
            for (int ic = 0; ic < 8; ++ic)
#pragma unroll
                for (int j = 0; j < K - 1; ++j) W1[ic][j] = W1[ic][j + 2];
            float colA[8], colB[8];
            hp1_col<K>(xb, 2 * s + P + 2, w1, b1, colA);
            hp1_col<K>(xb, 2 * s + P + 3, w1, b1, colB);
#pragma unroll
            for (int ic = 0; ic < 8; ++ic) {
                W1[ic][K - 1] = colA[ic];
                W1[ic][K]     = colB[ic];
            }
        }
    }
}

__global__ __launch_bounds__(64) void feats_kernel(
    const f16* __restrict__ xT,
    const float* __restrict__ hw1, const float* __restrict__ hb1,
    const float* __restrict__ hw2, const float* __restrict__ hb2,
    const float* __restrict__ hw3, const float* __restrict__ hb3,
    const float* __restrict__ lw1, const float* __restrict__ lb1,
    const float* __restrict__ lw2, const float* __restrict__ lb2,
    const float* __restrict__ lw3, const float* __restrict__ lb3,
    f16* __restrict__ featsH) {
    __shared__ u32 obufw[64 * 54];  // 64 rows x 108 f16
    const int c = blockIdx.x;
    const int bbase = blockIdx.y * 64;
    const int b = bbase + threadIdx.x;
    const f16* xb = xT + (size_t)c * BSZ + b;  // element l at xb[l*XSTR]
    f16* obuf = (f16*)obufw + threadIdx.x * 108;

    // high branch (K=7): features 0..3
    run_branch<7>(xb, hw1 + c * 56, hb1 + c * 8, hw2 + c * 224, hb2 + c * 4,
                  hw3 + c * 112, hb3 + c * 4, obuf);
    // low branch (K=3): features 4..7
    run_branch<3>(xb, lw1 + c * 24, lb1 + c * 8, lw2 + c * 96, lb2 + c * 4,
                  lw3 + c * 48, lb3 + c * 4, obuf + 48);
    // residual pooling: feature 8
#pragma unroll
    for (int t = 0; t < 12; ++t) {
        float s = 0.f;
#pragma unroll
        for (int j = 0; j < 8; ++j) s += ldx(xb, 8 * t + j);
        obuf[96 + t] = (f16)(s * 0.125f);
    }
    __syncthreads();

    // cooperative coalesced write-out: row r is 54 contiguous u32
    const int t = threadIdx.x;
    if (t < 54) {
        u32* dst = (u32*)featsH;
        for (int r = 0; r < 64; ++r)
            dst[(size_t)(bbase + r) * (KPAD / 2) + c * 54 + t] = obufw[r * 54 + t];
    }
}

// zero the K-padding columns of feats
__global__ void pad_feats(f16* __restrict__ featsH) {
    int b = blockIdx.x;
    int t = threadIdx.x;
    if (t < KPAD - KFEAT) featsH[(size_t)b * KPAD + KFEAT + t] = (f16)0.f;
}

// convert fw1 (1936 x 7128 f32) -> padded f16 (2048 x 7168), zero-filled pad
__global__ void cvt_fw1(const float* __restrict__ fw1, f16* __restrict__ dst) {
    int n = blockIdx.y;
    int k = blockIdx.x * 256 + threadIdx.x;
    float v = (n < NOUT && k < KFEAT) ? fw1[(size_t)n * KFEAT + k] : 0.f;
    dst[(size_t)n * KPAD + k] = (f16)v;
}

// ---------------------------------------------------------------- FC1 GEMM
// C[m][n] = sum_k A[m][k] * Bw[n][k];  H = relu(C + fb1) stored f16.
__global__ __launch_bounds__(256) void fc1_gemm(
    const f16* __restrict__ A, const f16* __restrict__ Bw,
    const float* __restrict__ fb1, f16* __restrict__ H) {
    __shared__ f16 lds_a[128 * 32];
    __shared__ f16 lds_b[128 * 32];
    const int tid = threadIdx.x;
    const int bm = blockIdx.x;  // 32 tiles of M
    const int bn = blockIdx.y;  // 16 tiles of N
    const int wid = tid >> 6, lane = tid & 63;
    const int wm = wid >> 1, wn = wid & 1;

    f32x4 acc[4][4];
#pragma unroll
    for (int i = 0; i < 4; ++i)
#pragma unroll
        for (int j = 0; j < 4; ++j) acc[i][j] = (f32x4){0.f, 0.f, 0.f, 0.f};

    const f16* Abase = A + (size_t)bm * 128 * KPAD;
    const f16* Bbase = Bw + (size_t)bn * 128 * KPAD;

    const int l15 = lane & 15, lhi = lane >> 4;

    for (int k0 = 0; k0 < KPAD; k0 += 32) {
        __syncthreads();
#pragma unroll
        for (int p = 0; p < 2; ++p) {
            int flat = p * 256 + tid;
            int row = flat >> 2, kc = flat & 3;
            gload_lds16(Abase + (size_t)row * KPAD + k0 + kc * 8, (char*)lds_a + flat * 16);
            gload_lds16(Bbase + (size_t)row * KPAD + k0 + kc * 8, (char*)lds_b + flat * 16);
        }
        __syncthreads();

        f16x8 af[4], bf[4];
#pragma unroll
        for (int i = 0; i < 4; ++i) {
            int m = wm * 64 + i * 16 + l15;
            af[i] = *(const f16x8*)(lds_a + m * 32 + lhi * 8);
            int n = wn * 64 + i * 16 + l15;
            bf[i] = *(const f16x8*)(lds_b + n * 32 + lhi * 8);
        }
#pragma unroll
        for (int i = 0; i < 4; ++i)
#pragma unroll
            for (int j = 0; j < 4; ++j)
                acc[i][j] = __builtin_amdgcn_mfma_f32_16x16x32_f16(af[i], bf[j], acc[i][j], 0, 0, 0);
    }

    // epilogue: C/D layout col = lane&15, row = (lane>>4)*4 + r
#pragma unroll
    for (int i = 0; i < 4; ++i) {
#pragma unroll
        for (int j = 0; j < 4; ++j) {
            int n = bn * 128 + wn * 64 + j * 16 + l15;
            float bias = (n < NOUT) ? fb1[n] : 0.f;
#pragma unroll
            for (int r = 0; r < 4; ++r) {
                int m = bm * 128 + wm * 64 + i * 16 + lhi * 4 + r;
                float v = acc[i][j][r] + bias;
                H[(size_t)m * NPAD + n] = (f16)fmaxf(v, 0.f);
            }
        }
    }
}

// ---------------------------------------------------------------- FC2
__global__ __launch_bounds__(64) void fc2_kernel(const f16* __restrict__ H,
                                                 const float* __restrict__ fw2,
                                                 const float* __restrict__ fb2,
                                                 float* __restrict__ out) {
    const int b = blockIdx.x;
    const int t = threadIdx.x;
    const f16* hb = H + (size_t)b * NPAD;
    float acc[14];
#pragma unroll
    for (int o = 0; o < 14; ++o) acc[o] = 0.f;
    for (int k = t; k < NOUT; k += 64) {
        float hv = (float)hb[k];
#pragma unroll
        for (int o = 0; o < 14; ++o) acc[o] += hv * fw2[o * NOUT + k];
    }
#pragma unroll
    for (int o = 0; o < 14; ++o) {
        float v = acc[o];
#pragma unroll
        for (int off = 32; off > 0; off >>= 1) v += __shfl_down(v, off, 64);
        if (t == 0) out[b * 14 + o] = v + fb2[o];
    }
}

// ---------------------------------------------------------------- launcher
extern "C" void kernel_launch(void* const* d_in, const int* in_sizes, int n_in,
                              void* d_out, int out_size, void* d_ws, size_t ws_size,
                              hipStream_t stream) {
    const float* x   = (const float*)d_in[0];
    const float* hw1 = (const float*)d_in[1];
    const float* hb1 = (const float*)d_in[2];
    const float* hw2 = (const float*)d_in[3];
    const float* hb2 = (const float*)d_in[4];
    const float* hw3 = (const float*)d_in[5];
    const float* hb3 = (const float*)d_in[6];
    const float* lw1 = (const float*)d_in[7];
    const float* lb1 = (const float*)d_in[8];
    const float* lw2 = (const float*)d_in[9];
    const float* lb2 = (const float*)d_in[10];
    const float* lw3 = (const float*)d_in[11];
    const float* lb3 = (const float*)d_in[12];
    const float* fw1 = (const float*)d_in[13];
    const float* fb1 = (const float*)d_in[14];
    const float* fw2 = (const float*)d_in[15];
    const float* fb2 = (const float*)d_in[16];

    f16* featsH = (f16*)d_ws;                               // 4096*7168 f16 = 58.7 MB
    f16* fw1H   = featsH + (size_t)BSZ * KPAD;              // 2048*7168 f16 = 29.4 MB
    f16* h      = fw1H + (size_t)NPAD * KPAD;               // 4096*2048 f16 = 16.8 MB
    f16* xT     = h + (size_t)BSZ * NPAD;                   // 6600*4096 f16 = 54.1 MB

    transpose_x<<<dim3((LC + 31) / 32, BSZ / 32), 256, 0, stream>>>(x, xT);
    feats_kernel<<<dim3(CCH, BSZ / 64), 64, 0, stream>>>(
        xT, hw1, hb1, hw2, hb2, hw3, hb3, lw1, lb1, lw2, lb2, lw3, lb3, featsH);
    pad_feats<<<dim3(BSZ), 64, 0, stream>>>(featsH);
    cvt_fw1<<<dim3(KPAD / 256, NPAD), 256, 0, stream>>>(fw1, fw1H);
    fc1_gemm<<<dim3(BSZ / 128, NPAD / 128), 256, 0, stream>>>(featsH, fw1H, fb1, h);
    fc2_kernel<<<dim3(BSZ), 64, 0, stream>>>(h, fw2, fb2, (float*)d_out);
}